// Round 7
// baseline (226.903 us; speedup 1.0000x reference)
//
#include <hip/hip_runtime.h>

// FourierMixer: ifft2(fft2(x)) on real x == identity (absmax 0.016 vs thr
// 0.108, verified). Pure HBM-bound copy: 128 MiB in + 128 MiB out.
//
// History (kernel-only times; 2 re-poison 512MiB fills ~160 us are fixed):
//  R0-R2: strided nontemporal float4 -> ~70 us (3.8 TB/s).
//  R3:    block-contiguous 32 KiB tiles, 4096 blk x 256 thr x 8 float4,
//         nt both -> ~57 us (4.7 TB/s). BEST total: 217.4 us.
//  R4/R5: 2048 blk x 16 float4 -> ~66 us. REFUTED.
//  R6:    hipMemcpyAsync blit -> ~66 us. REFUTED.
//  R7:    default cache policy -> ~65 us. nt is better; kept.
//  R8:    per-wave sequential 8 KiB streams -> ~57 us. NEUTRAL.
//  R9:    few-DEEP-streams hypothesis, copied from fillBuffer's own
//         counters (VGPR=8, Occupancy 9.4% => ~770 waves streaming
//         ~700 KB each sequentially at 6.7 TB/s). All our variants used
//         ~16K micro-streams. This one: 512 blocks x 4 waves = 2048
//         waves, each owning a contiguous 64 KiB stretch, tight unroll-1
//         loop of 8-deep 1 KiB-line batches. If neutral: declare
//         roofline ~217 us (4.7 TB/s mixed-copy floor + fixed fills).
//
// N = 33,554,432 floats = 8,388,608 float4 = 512 blk * 4 waves * 4096.

typedef float v4f __attribute__((ext_vector_type(4)));

__global__ __launch_bounds__(256) void fourier_mixer_copy(
    const v4f* __restrict__ in, v4f* __restrict__ out) {
  const unsigned wave = threadIdx.x >> 6;   // 0..3
  const unsigned lane = threadIdx.x & 63u;  // 0..63
  // Wave (blockIdx*4 + wave) owns float4 range [waveId*4096, +4096)
  // = 64 KiB contiguous, walked front-to-back.
  const unsigned base = (blockIdx.x * 4u + wave) * 4096u + lane;
#pragma unroll 1
  for (unsigned j = 0; j < 8u; ++j) {
    const unsigned b = base + j * 512u;  // 8 KiB step per iteration
    // 8 sequential 1 KiB lines, 8-deep in flight, then mirrored stores.
    v4f r0 = __builtin_nontemporal_load(&in[b + 0u * 64u]);
    v4f r1 = __builtin_nontemporal_load(&in[b + 1u * 64u]);
    v4f r2 = __builtin_nontemporal_load(&in[b + 2u * 64u]);
    v4f r3 = __builtin_nontemporal_load(&in[b + 3u * 64u]);
    v4f r4 = __builtin_nontemporal_load(&in[b + 4u * 64u]);
    v4f r5 = __builtin_nontemporal_load(&in[b + 5u * 64u]);
    v4f r6 = __builtin_nontemporal_load(&in[b + 6u * 64u]);
    v4f r7 = __builtin_nontemporal_load(&in[b + 7u * 64u]);
    __builtin_nontemporal_store(r0, &out[b + 0u * 64u]);
    __builtin_nontemporal_store(r1, &out[b + 1u * 64u]);
    __builtin_nontemporal_store(r2, &out[b + 2u * 64u]);
    __builtin_nontemporal_store(r3, &out[b + 3u * 64u]);
    __builtin_nontemporal_store(r4, &out[b + 4u * 64u]);
    __builtin_nontemporal_store(r5, &out[b + 5u * 64u]);
    __builtin_nontemporal_store(r6, &out[b + 6u * 64u]);
    __builtin_nontemporal_store(r7, &out[b + 7u * 64u]);
  }
}

extern "C" void kernel_launch(void* const* d_in, const int* in_sizes, int n_in,
                              void* d_out, int out_size, void* d_ws, size_t ws_size,
                              hipStream_t stream) {
  const v4f* x = (const v4f*)d_in[0];
  v4f* y = (v4f*)d_out;
  // 8,388,608 float4s exactly = 512 blocks * 256 threads * 64 per thread
  fourier_mixer_copy<<<512, 256, 0, stream>>>(x, y);
}

// Round 8
// 216.503 us; speedup vs baseline: 1.0480x; 1.0480x over previous
//
#include <hip/hip_runtime.h>

// FourierMixer: ifft2(fft2(x)) on real x == identity (absmax 0.016 vs thr
// 0.108, verified). Pure HBM-bound copy: 128 MiB in + 128 MiB out.
//
// FINAL KERNEL = R3 geometry, the measured optimum (217.4 us total).
//
// History (kernel-only times; 2 re-poison 512MiB fills ~160 us are fixed
// harness overhead in the timed region):
//  R0-R2: strided nontemporal float4 -> ~70 us (3.8 TB/s).
//  R3:    block-contiguous 32 KiB tiles, 4096 blk x 256 thr x 8 float4,
//         nt both -> ~57 us (4.7 TB/s). BEST total: 217.4 us.
//  R4/R5: 2048 blk x 16 float4/thr -> ~66 us. REFUTED (tail imbalance).
//  R6:    hipMemcpyAsync blit -> ~66 us. REFUTED (not the tuned path).
//  R7:    default cache policy -> ~65 us. nt is better; kept.
//  R8:    per-wave sequential 8 KiB streams -> ~57 us. NEUTRAL.
//  R9:    512 blk few-deep-streams (fillBuffer structure) -> ~68 us.
//         REFUTED (write-only structure doesn't transfer to copy).
//
// Structural ceiling: every axis A/B'd — stream count 2K..16K, depth
// 8..64, sequentiality, cache policy, driver blit. Both directions away
// from R3 are worse => ~4.7 TB/s is the mixed 1:1 read+write floor for a
// 268 MB transfer here (vs 6.29 TB/s idealized steady-state copy).
//
// N = 33,554,432 floats = 8,388,608 float4 = 4096 blocks * 256 thr * 8.

typedef float v4f __attribute__((ext_vector_type(4)));

__global__ __launch_bounds__(256) void fourier_mixer_copy(
    const v4f* __restrict__ in, v4f* __restrict__ out) {
  // Block b covers float4 indices [b*2048, (b+1)*2048)  (32 KiB tile).
  const unsigned base = blockIdx.x * 2048u + threadIdx.x;
  // 8 independent fully-coalesced 16B nontemporal loads (per-wave: 1 KiB
  // lines at 4 KiB stride inside the block tile), then 8 mirrored stores.
  v4f r0 = __builtin_nontemporal_load(&in[base + 0u * 256u]);
  v4f r1 = __builtin_nontemporal_load(&in[base + 1u * 256u]);
  v4f r2 = __builtin_nontemporal_load(&in[base + 2u * 256u]);
  v4f r3 = __builtin_nontemporal_load(&in[base + 3u * 256u]);
  v4f r4 = __builtin_nontemporal_load(&in[base + 4u * 256u]);
  v4f r5 = __builtin_nontemporal_load(&in[base + 5u * 256u]);
  v4f r6 = __builtin_nontemporal_load(&in[base + 6u * 256u]);
  v4f r7 = __builtin_nontemporal_load(&in[base + 7u * 256u]);
  __builtin_nontemporal_store(r0, &out[base + 0u * 256u]);
  __builtin_nontemporal_store(r1, &out[base + 1u * 256u]);
  __builtin_nontemporal_store(r2, &out[base + 2u * 256u]);
  __builtin_nontemporal_store(r3, &out[base + 3u * 256u]);
  __builtin_nontemporal_store(r4, &out[base + 4u * 256u]);
  __builtin_nontemporal_store(r5, &out[base + 5u * 256u]);
  __builtin_nontemporal_store(r6, &out[base + 6u * 256u]);
  __builtin_nontemporal_store(r7, &out[base + 7u * 256u]);
}

extern "C" void kernel_launch(void* const* d_in, const int* in_sizes, int n_in,
                              void* d_out, int out_size, void* d_ws, size_t ws_size,
                              hipStream_t stream) {
  const v4f* x = (const v4f*)d_in[0];
  v4f* y = (v4f*)d_out;
  // 8,388,608 float4s exactly = 4096 blocks * 256 threads * 8 per thread
  fourier_mixer_copy<<<4096, 256, 0, stream>>>(x, y);
}